// Round 16
// baseline (269.141 us; speedup 1.0000x reference)
//
#include <hip/hip_runtime.h>

#define Bn 4
#define Tn 8192
#define Dn 512
#define GC 512
#define NG 16
#define ALPHAc 0.03f

typedef unsigned short u16;
typedef short bf8_t __attribute__((ext_vector_type(8)));
typedef float f4_t  __attribute__((ext_vector_type(4)));
typedef u16 us8_t __attribute__((ext_vector_type(8)));
typedef u16 us4_t __attribute__((ext_vector_type(4)));

#define MFMA16(a,b,c) __builtin_amdgcn_mfma_f32_16x16x32_bf16((a),(b),(c),0,0,0)

__device__ __forceinline__ u16 f2bf(float f) {
  union { float f; unsigned u; } v; v.f = f;
  unsigned r = v.u + 0x7fffu + ((v.u >> 16) & 1u);
  return (u16)(r >> 16);
}
__device__ __forceinline__ float bf2f(u16 h) {
  union { unsigned u; float f; } v; v.u = ((unsigned)h) << 16;
  return v.f;
}
// async global->LDS, 16B per lane; LDS dest wave-uniform base (HW adds lane*16)
__device__ __forceinline__ void gload_lds16(const u16* g, u16* l) {
  __builtin_amdgcn_global_load_lds(
      (const __attribute__((address_space(1))) void*)g,
      (__attribute__((address_space(3))) void*)l, 16, 0, 0);
}

// ---------------- fp32 -> bf16 convert ----------------
__global__ __launch_bounds__(256) void k_convert(const float* __restrict__ src,
                                                 u16* __restrict__ dst, int n4) {
  int i = blockIdx.x * 256 + threadIdx.x;
  if (i >= n4) return;
  float4 v = ((const float4*)src)[i];
  us4_t o = { f2bf(v.x), f2bf(v.y), f2bf(v.z), f2bf(v.w) };
  ((us4_t*)dst)[i] = o;
}

// ---------------- transpose+shift+SCALE: wkTg[b][e][t] = out[b,t-1,e] * gw(t) ----------------
// gw(t) = gamma^(GC-1 - t%GC). wkTg consumed ONLY by k_gemm_u (scale folded here).
__global__ __launch_bounds__(256) void k_wkT(const u16* __restrict__ src,
                                             u16* __restrict__ dst,
                                             const float* __restrict__ decay) {
  __shared__ u16 T[128*129];
  const int tid = threadIdx.x;
  const int t0 = blockIdx.x * 128, e0 = blockIdx.y * 128;
  const int b = blockIdx.z;
  const size_t bT = (size_t)b * Tn;
  const float gamma = 1.f / (1.f + __builtin_expf(-decay[0]));
  const float l2g = __builtin_log2f(gamma);
#pragma unroll
  for (int i = 0; i < 8; ++i) {
    int slot = i*256 + tid;
    int row = slot >> 4, c8 = (slot & 15) << 3;
    int tg = t0 + row - 1;
    us8_t v8 = {0,0,0,0,0,0,0,0};
    if (tg >= 0) v8 = *(const us8_t*)&src[(bT + tg)*Dn + e0 + c8];
    const float gw = __builtin_exp2f(l2g * (float)(GC - 1 - ((t0 + row) & (GC - 1))));
#pragma unroll
    for (int k = 0; k < 8; ++k) T[row*129 + c8 + k] = f2bf(bf2f(v8[k]) * gw);
  }
  __syncthreads();
#pragma unroll
  for (int i = 0; i < 8; ++i) {
    int slot = i*256 + tid;
    int e = slot >> 4, t8 = (slot & 15) << 3;
    us8_t o;
#pragma unroll
    for (int k = 0; k < 8; ++k) o[k] = T[(t8 + k)*129 + e];
    *(us8_t*)&dst[((size_t)b*Dn + e0 + e)*Tn + t0 + t8] = o;
  }
}

// ---------------- K1: vT = (out @ w_write^T)^T, m97-style staged ----------------
__global__ __launch_bounds__(256) void k_gemm_v(const u16* __restrict__ A,
                                                const u16* __restrict__ Bm,
                                                u16* __restrict__ vT) {
  __shared__ u16 lds[128*136];
  u16* As = lds;
  u16* Bs = lds + 128*64;
  const int tid = threadIdx.x;
  const int lane = tid & 63, w = tid >> 6;
  const int g = lane >> 4, lr = lane & 15;
  const int rl = lane >> 3, cb = (lane & 7) * 8;
  const int m0 = blockIdx.y * 128, n0 = blockIdx.x * 128;
  const int wm = (w >> 1) * 64, wn = (w & 1) * 64;
  f4_t acc[4][4];
#pragma unroll
  for (int i = 0; i < 4; ++i)
#pragma unroll
    for (int j = 0; j < 4; ++j) acc[i][j] = (f4_t){0.f, 0.f, 0.f, 0.f};

  for (int kb = 0; kb < 8; ++kb) {
    const int k0 = kb * 64;
    __syncthreads();
#pragma unroll
    for (int i = 0; i < 4; ++i) {
      int r0 = (w*4 + i) * 8;
      gload_lds16(&A[(size_t)(m0 + r0 + rl)*Dn + k0 + cb], &As[r0*64]);
      gload_lds16(&Bm[(size_t)(n0 + r0 + rl)*Dn + k0 + cb], &Bs[r0*64]);
    }
    __syncthreads();
#pragma unroll
    for (int kk = 0; kk < 2; ++kk) {
      const int co = kk*32 + g*8;
      bf8_t a[4], b[4];
#pragma unroll
      for (int mf = 0; mf < 4; ++mf) a[mf] = *(const bf8_t*)&As[(wm + mf*16 + lr)*64 + co];
#pragma unroll
      for (int nf = 0; nf < 4; ++nf) b[nf] = *(const bf8_t*)&Bs[(wn + nf*16 + lr)*64 + co];
#pragma unroll
      for (int mf = 0; mf < 4; ++mf)
#pragma unroll
        for (int nf = 0; nf < 4; ++nf)
          acc[mf][nf] = MFMA16(a[mf], b[nf], acc[mf][nf]);
    }
  }
  __syncthreads();
  u16* Cs = lds;  // [128 d][136 t]
#pragma unroll
  for (int mf = 0; mf < 4; ++mf)
#pragma unroll
    for (int nf = 0; nf < 4; ++nf)
#pragma unroll
      for (int r = 0; r < 4; ++r)
        Cs[(wn + nf*16 + lr)*136 + (wm + mf*16 + g*4 + r)] = f2bf(acc[mf][nf][r]);
  __syncthreads();
  const int b = m0 >> 13;
  const int tt0 = m0 & 8191;
#pragma unroll
  for (int i = 0; i < 8; ++i) {
    int slot = i * 256 + tid;
    int d = slot >> 4, t8 = (slot & 15) << 3;
    *(us8_t*)&vT[((size_t)b*Dn + n0 + d)*Tn + tt0 + t8] = *(const us8_t*)&Cs[d*136 + t8];
  }
}

// ---------------- K2: U_g[d][e] = sum_t vT[d][t]*wkTg[e][t], m97-style staged ----------------
__global__ __launch_bounds__(256) void k_gemm_u(const u16* __restrict__ vT,
                                                const u16* __restrict__ wkTg,
                                                u16* __restrict__ U) {
  __shared__ u16 lds[128*64*2];
  u16* As = lds;
  u16* Bs = lds + 128*64;
  const int tid = threadIdx.x;
  const int lane = tid & 63, w = tid >> 6;
  const int g = lane >> 4, lr = lane & 15;
  const int rl = lane >> 3, cb = (lane & 7) * 8;
  const int d0 = blockIdx.y * 128, e0 = blockIdx.x * 128;
  const int bg = blockIdx.z;
  const int b = bg >> 4, gg = bg & 15;
  const int wm = (w >> 1) * 64, wn = (w & 1) * 64;
  const size_t kbase = (size_t)gg * GC;
  f4_t acc[4][4];
#pragma unroll
  for (int i = 0; i < 4; ++i)
#pragma unroll
    for (int j = 0; j < 4; ++j) acc[i][j] = (f4_t){0.f, 0.f, 0.f, 0.f};

  for (int kb = 0; kb < 8; ++kb) {
    const int k0 = kb * 64;
    __syncthreads();
#pragma unroll
    for (int i = 0; i < 4; ++i) {
      int r0 = (w*4 + i) * 8;
      gload_lds16(&vT[((size_t)b*Dn + d0 + r0 + rl)*Tn + kbase + k0 + cb], &As[r0*64]);
      gload_lds16(&wkTg[((size_t)b*Dn + e0 + r0 + rl)*Tn + kbase + k0 + cb], &Bs[r0*64]);
    }
    __syncthreads();
#pragma unroll
    for (int kk = 0; kk < 2; ++kk) {
      const int co = kk*32 + g*8;
      bf8_t a[4], bb[4];
#pragma unroll
      for (int mf = 0; mf < 4; ++mf) a[mf] = *(const bf8_t*)&As[(wm + mf*16 + lr)*64 + co];
#pragma unroll
      for (int nf = 0; nf < 4; ++nf) bb[nf] = *(const bf8_t*)&Bs[(wn + nf*16 + lr)*64 + co];
#pragma unroll
      for (int mf = 0; mf < 4; ++mf)
#pragma unroll
        for (int nf = 0; nf < 4; ++nf)
          acc[mf][nf] = MFMA16(a[mf], bb[nf], acc[mf][nf]);
    }
  }
  const size_t ub = (size_t)bg * Dn * Dn;
#pragma unroll
  for (int mf = 0; mf < 4; ++mf)
#pragma unroll
    for (int nf = 0; nf < 4; ++nf)
#pragma unroll
      for (int r = 0; r < 4; ++r)
        U[ub + (size_t)(d0 + wm + mf*16 + g*4 + r)*Dn + e0 + wn + nf*16 + lr] = f2bf(acc[mf][nf][r]);
}

// ---------------- K3: 16-step scan over chunk totals -> Wb[b][g] (bf16, pre-update) ----------------
__global__ __launch_bounds__(256) void k_bscan(const u16* __restrict__ U,
                                               u16* __restrict__ Wb,
                                               const float* __restrict__ decay) {
  const int tid = threadIdx.x;
  const int d0 = blockIdx.x * 64, e0 = blockIdx.y * 64;
  const int b = blockIdx.z;
  const float gamma = 1.f / (1.f + __builtin_expf(-decay[0]));
  const float gCC = __builtin_exp2f(__builtin_log2f(gamma) * (float)GC);
  const int colb = (tid & 15) << 2;
  const int rowb = (tid >> 4) << 2;
  float st[4][4];
#pragma unroll
  for (int rr = 0; rr < 4; ++rr)
#pragma unroll
    for (int cc = 0; cc < 4; ++cc) st[rr][cc] = 0.f;

  for (int gg = 0; gg < NG; ++gg) {
    const size_t base = (size_t)(b*NG + gg) * Dn * Dn;
#pragma unroll
    for (int rr = 0; rr < 4; ++rr) {
      us4_t o = { f2bf(st[rr][0]), f2bf(st[rr][1]), f2bf(st[rr][2]), f2bf(st[rr][3]) };
      *(us4_t*)&Wb[base + (size_t)(d0 + rowb + rr)*Dn + e0 + colb] = o;
      us4_t u4 = *(const us4_t*)&U[base + (size_t)(d0 + rowb + rr)*Dn + e0 + colb];
      st[rr][0] = gCC*st[rr][0] + bf2f(u4.x);
      st[rr][1] = gCC*st[rr][1] + bf2f(u4.y);
      st[rr][2] = gCC*st[rr][2] + bf2f(u4.z);
      st[rr][3] = gCC*st[rr][3] + bf2f(u4.w);
    }
  }
}

// ---------------- K4: binter = gamma^{tloc} * rk_g @ Wb_g^T, m97-style staged ----------------
__global__ __launch_bounds__(256) void k_binter(const u16* __restrict__ out_bf,
                                                const u16* __restrict__ Wb,
                                                u16* __restrict__ binter,
                                                const float* __restrict__ decay) {
  __shared__ u16 lds[128*136];
  u16* As = lds;
  u16* Bs = lds + 128*64;
  const int tid = threadIdx.x;
  const int lane = tid & 63, w = tid >> 6;
  const int g = lane >> 4, lr = lane & 15;
  const int rl = lane >> 3, cb = (lane & 7) * 8;
  const int m0 = blockIdx.y * 128, n0 = blockIdx.x * 128;
  const int z = blockIdx.z;
  const int b = z / 15, gg = z % 15 + 1;
  const int wm = (w >> 1) * 64, wn = (w & 1) * 64;
  const float gamma = 1.f / (1.f + __builtin_expf(-decay[0]));
  const float l2g = __builtin_log2f(gamma);
  const size_t arow = (size_t)b*Tn + (size_t)gg*GC + m0;
  const size_t brow = (size_t)(b*NG + gg) * Dn * Dn;
  f4_t acc[4][4];
#pragma unroll
  for (int i = 0; i < 4; ++i)
#pragma unroll
    for (int j = 0; j < 4; ++j) acc[i][j] = (f4_t){0.f, 0.f, 0.f, 0.f};

  for (int kb = 0; kb < 8; ++kb) {
    const int k0 = kb * 64;
    __syncthreads();
#pragma unroll
    for (int i = 0; i < 4; ++i) {
      int r0 = (w*4 + i) * 8;
      gload_lds16(&out_bf[(arow + r0 + rl)*Dn + k0 + cb], &As[r0*64]);
      gload_lds16(&Wb[brow + (size_t)(n0 + r0 + rl)*Dn + k0 + cb], &Bs[r0*64]);
    }
    __syncthreads();
#pragma unroll
    for (int kk = 0; kk < 2; ++kk) {
      const int co = kk*32 + g*8;
      bf8_t a[4], bb[4];
#pragma unroll
      for (int mf = 0; mf < 4; ++mf) a[mf] = *(const bf8_t*)&As[(wm + mf*16 + lr)*64 + co];
#pragma unroll
      for (int nf = 0; nf < 4; ++nf) bb[nf] = *(const bf8_t*)&Bs[(wn + nf*16 + lr)*64 + co];
#pragma unroll
      for (int mf = 0; mf < 4; ++mf)
#pragma unroll
        for (int nf = 0; nf < 4; ++nf)
          acc[mf][nf] = MFMA16(a[mf], bb[nf], acc[mf][nf]);
    }
  }
  __syncthreads();
  u16* Cs = lds;  // [128 t][136 d]
#pragma unroll
  for (int mf = 0; mf < 4; ++mf) {
#pragma unroll
    for (int r = 0; r < 4; ++r) {
      const float gp = __builtin_exp2f(l2g * (float)(m0 + wm + mf*16 + g*4 + r));
#pragma unroll
      for (int nf = 0; nf < 4; ++nf)
        Cs[(wm + mf*16 + g*4 + r)*136 + wn + nf*16 + lr] = f2bf(acc[mf][nf][r] * gp);
    }
  }
  __syncthreads();
#pragma unroll
  for (int i = 0; i < 8; ++i) {
    int slot = i * 256 + tid;
    int r = slot >> 4, c8 = (slot & 15) << 3;
    *(us8_t*)&binter[(arow + r)*Dn + n0 + c8] = *(const us8_t*)&Cs[r*136 + c8];
  }
}

// ---------------- K5: intra v8 — v6 + lgkm-only (B) + setprio around MFMA clusters ----------------
// grid (16 gg, 4 qt2, 4 b) x 512 thr. LDS 151,552 B (1 WG/CU, 2 waves/SIMD).
__global__ __launch_bounds__(512, 2) void k_intra(const u16* __restrict__ out_bf,
                                                  const u16* __restrict__ vT,
                                                  const u16* __restrict__ binter,
                                                  u16* __restrict__ reads_bf,
                                                  const float* __restrict__ decay) {
  __shared__ u16 WK2[2*64*520];   // wk double-buffer [p][s 64][e 512 (+8 pad)]
  __shared__ u16 PS[128*72];      // P [t 128][s 64 (+8 pad)]
  const int tid = threadIdx.x;
  const int lane = tid & 63, w = tid >> 6;   // 8 waves
  const int g = lane >> 4, lr = lane & 15;
  const int gg = blockIdx.x, qt2 = blockIdx.y, b = blockIdx.z;
  const int jmax = 2*qt2 + 2;
  const float gamma = 1.f / (1.f + __builtin_expf(-decay[0]));
  const float l2g = __builtin_log2f(gamma);
  const size_t bT = (size_t)b * Tn;
  const size_t tbase = bT + (size_t)gg*GC + qt2*128;

  // QKT A-operand: wave w owns t-strip w*16; rk row in regs, loaded once
  bf8_t rk[16];
#pragma unroll
  for (int kk = 0; kk < 16; ++kk)
    rk[kk] = *(const bf8_t*)&out_bf[(tbase + w*16 + lr)*Dn + kk*32 + g*8];

  // PV A-operand base: d row = w*64 + mf*16 + lr (XCD-L2-local via gg swizzle)
  const u16* vbase = vT + ((size_t)b*Dn + w*64 + lr)*Tn + (size_t)gg*GC + g*8;

  f4_t acc[4][8];   // [mf: d 64][nf: t 128]
#pragma unroll
  for (int i = 0; i < 4; ++i)
#pragma unroll
    for (int j = 0; j < 8; ++j) acc[i][j] = (f4_t){0.f, 0.f, 0.f, 0.f};

#define STAGE_J(JJ, P)                                                        \
  {                                                                           \
    const int sgs = gg*GC + (JJ)*64;                                          \
    u16* sbase = &WK2[(P)*64*520];                                            \
    _Pragma("unroll")                                                         \
    for (int i = 0; i < 8; ++i) {                                             \
      int row = i*8 + w;                                                      \
      int wr = sgs + row - 1;                                                 \
      if (wr < 0) wr = 0;  /* only (gg==0,j==0,row==0); zero-fixed below */   \
      gload_lds16(&out_bf[(bT + (size_t)wr)*Dn + lane*8], &sbase[row*520]);   \
    }                                                                         \
  }

  STAGE_J(0, 0);
  __syncthreads();                 // drain stage(0)
  if (gg == 0 && tid < 64) {       // global t=0: wk row is zero
    us8_t z = {0,0,0,0,0,0,0,0};
    *(us8_t*)&WK2[tid*8] = z;
  }
  __syncthreads();

  for (int j = 0; j < jmax; ++j) {
    const int p = j & 1;
    if (j + 1 < jmax) STAGE_J(j + 1, p ^ 1);   // async; stays in flight across (B)
    const u16* buf = &WK2[p*64*520];
    f4_t sacc[4];
#pragma unroll
    for (int i = 0; i < 4; ++i) sacc[i] = (f4_t){0.f, 0.f, 0.f, 0.f};
    __builtin_amdgcn_s_setprio(1);
#pragma unroll
    for (int kk = 0; kk < 16; ++kk) {
      const int co = kk*32 + g*8;
#pragma unroll
      for (int nf = 0; nf < 4; ++nf) {
        bf8_t bb = *(const bf8_t*)&buf[(nf*16 + lr)*520 + co];
        sacc[nf] = MFMA16(rk[kk], bb, sacc[nf]);
      }
    }
    __builtin_amdgcn_s_setprio(0);
    // mask+decay -> PS[t][s]; thread holds tt = w*16+g*4+r, ss = nf*16+lr
    const int off = qt2*128 - j*64;
#pragma unroll
    for (int nf = 0; nf < 4; ++nf) {
#pragma unroll
      for (int r = 0; r < 4; ++r) {
        const int tt = w*16 + g*4 + r;
        const int ss = nf*16 + lr;
        const int dd = off + tt - ss;
        float mval = (dd > 0) ? __builtin_exp2f(l2g * (float)(dd - 1)) : 0.f;
        PS[tt*72 + ss] = f2bf(sacc[nf][r] * mval);
      }
    }
    // (B): lgkm-only barrier — stage(j+1) vmcnt NOT drained (stays in flight)
    asm volatile("s_waitcnt lgkmcnt(0)" ::: "memory");
    __builtin_amdgcn_sched_barrier(0);
    __builtin_amdgcn_s_barrier();
    // PV: acc[d][t] += vT x P over this s-block
    __builtin_amdgcn_s_setprio(1);
#pragma unroll
    for (int kk = 0; kk < 2; ++kk) {
      const int co = kk*32 + g*8;
      bf8_t a[4], bb[8];
#pragma unroll
      for (int mf = 0; mf < 4; ++mf)
        a[mf] = *(const bf8_t*)(vbase + (size_t)(mf*16)*Tn + j*64 + kk*32);
#pragma unroll
      for (int nf = 0; nf < 8; ++nf) bb[nf] = *(const bf8_t*)&PS[(nf*16 + lr)*72 + co];
#pragma unroll
      for (int mf = 0; mf < 4; ++mf)
#pragma unroll
        for (int nf = 0; nf < 8; ++nf)
          acc[mf][nf] = MFMA16(a[mf], bb[nf], acc[mf][nf]);
    }
    __builtin_amdgcn_s_setprio(0);
    __syncthreads();   // (A'): full drain — stage(j+1) landed; PS free for overwrite
  }
#undef STAGE_J

  // epilogue: two d-half passes via EP = WK2 [128 t][264]
  u16* EP = WK2;
#pragma unroll
  for (int pp = 0; pp < 2; ++pp) {
    __syncthreads();
    if ((w >> 2) == pp) {
      const int wq = w & 3;
#pragma unroll
      for (int mf = 0; mf < 4; ++mf)
#pragma unroll
        for (int nf = 0; nf < 8; ++nf)
#pragma unroll
          for (int r = 0; r < 4; ++r)
            EP[(nf*16 + lr)*264 + wq*64 + mf*16 + g*4 + r] = f2bf(acc[mf][nf][r]);
    }
    __syncthreads();
#pragma unroll
    for (int i = 0; i < 8; ++i) {
      int slot = i*512 + tid;
      int t = slot >> 5, d8 = (slot & 31) << 3;
      us8_t ev = *(const us8_t*)&EP[t*264 + d8];
      us8_t o;
      if (gg > 0) {
        us8_t bv = *(const us8_t*)&binter[(tbase + t)*Dn + pp*256 + d8];
#pragma unroll
        for (int k = 0; k < 8; ++k) o[k] = f2bf(bf2f(ev[k]) + bf2f(bv[k]));
      } else {
        o = ev;
      }
      *(us8_t*)&reads_bf[(tbase + t)*Dn + pp*256 + d8] = o;
    }
  }
}

// ---------------- K6: out = resid + alpha * (reads @ w_read^T), m97-style staged ----------------
__global__ __launch_bounds__(256) void k_final(const u16* __restrict__ A,
                                               const u16* __restrict__ Bm,
                                               const float* __restrict__ resid,
                                               float* __restrict__ Cout) {
  __shared__ u16 lds[128*64*2];
  u16* As = lds;
  u16* Bs = lds + 128*64;
  const int tid = threadIdx.x;
  const int lane = tid & 63, w = tid >> 6;
  const int g = lane >> 4, lr = lane & 15;
  const int rl = lane >> 3, cb = (lane & 7) * 8;
  const int m0 = blockIdx.y * 128, n0 = blockIdx.x * 128;
  const int wm = (w >> 1) * 64, wn = (w & 1) * 64;
  f4_t acc[4][4];
#pragma unroll
  for (int i = 0; i < 4; ++i)
#pragma unroll
    for (int j = 0; j < 4; ++j) acc[i][j] = (f4_t){0.f, 0.f, 0.f, 0.f};

  for (int kb = 0; kb < 8; ++kb) {
    const int k0 = kb * 64;
    __syncthreads();
#pragma unroll
    for (int i = 0; i < 4; ++i) {
      int r0 = (w*4 + i) * 8;
      gload_lds16(&A[(size_t)(m0 + r0 + rl)*Dn + k0 + cb], &As[r0*64]);
      gload_lds16(&Bm[(size_t)(n0 + r0 + rl)*Dn + k0 + cb], &Bs[r0*64]);
    }
    __syncthreads();
#pragma unroll
    for (int kk = 0; kk < 2; ++kk) {
      const int co = kk*32 + g*8;
      bf8_t a[4], b[4];
#pragma unroll
      for (int mf = 0; mf < 4; ++mf) a[mf] = *(const bf8_t*)&As[(wm + mf*16 + lr)*64 + co];
#pragma unroll
      for (int nf = 0; nf < 4; ++nf) b[nf] = *(const bf8_t*)&Bs[(wn + nf*16 + lr)*64 + co];
#pragma unroll
      for (int mf = 0; mf < 4; ++mf)
#pragma unroll
        for (int nf = 0; nf < 4; ++nf)
          acc[mf][nf] = MFMA16(a[mf], b[nf], acc[mf][nf]);
    }
  }
#pragma unroll
  for (int mf = 0; mf < 4; ++mf)
#pragma unroll
    for (int nf = 0; nf < 4; ++nf)
#pragma unroll
      for (int r = 0; r < 4; ++r) {
        int row = m0 + wm + mf*16 + g*4 + r;
        int col = n0 + wn + nf*16 + lr;
        int idx = row * Dn + col;
        Cout[idx] = resid[idx] + ALPHAc * acc[mf][nf][r];
      }
}

extern "C" void kernel_launch(void* const* d_in, const int* in_sizes, int n_in,
                              void* d_out, int out_size, void* d_ws, size_t ws_size,
                              hipStream_t stream) {
  const float* out_f   = (const float*)d_in[0];
  const float* w_write = (const float*)d_in[1];
  const float* w_read  = (const float*)d_in[2];
  const float* decay   = (const float*)d_in[3];
  float* outp = (float*)d_out;

  char* ws = (char*)d_ws;
  // NON-ALIASED layout (replay-overlap safe). Total 235,929,600 B.
  u16*   out_bf = (u16*)(ws);
  u16*   wkTg   = (u16*)(ws + (size_t)33554432);
  u16*   vT     = (u16*)(ws + (size_t)67108864);
  u16*   wwt_bf = (u16*)(ws + (size_t)100663296);
  u16*   wrd_bf = (u16*)(ws + (size_t)101187584);
  u16*   U      = (u16*)(ws + (size_t)101711872);
  u16*   binter = (u16*)(ws + (size_t)135266304);
  u16*   reads  = (u16*)(ws + (size_t)168820736);
  u16*   Wb     = (u16*)(ws + (size_t)202375168);

  k_convert<<<16384, 256, 0, stream>>>(out_f, out_bf, 4194304);
  k_convert<<<256, 256, 0, stream>>>(w_write, wwt_bf, 65536);
  k_convert<<<256, 256, 0, stream>>>(w_read, wrd_bf, 65536);
  k_wkT<<<dim3(64, 4, 4), 256, 0, stream>>>(out_bf, wkTg, decay);
  k_gemm_v<<<dim3(4, 256), 256, 0, stream>>>(out_bf, wwt_bf, vT);
  k_gemm_u<<<dim3(4, 4, 64), 256, 0, stream>>>(vT, wkTg, U);
  k_bscan<<<dim3(8, 8, 4), 256, 0, stream>>>(U, Wb, decay);
  k_binter<<<dim3(4, 4, 60), 256, 0, stream>>>(out_bf, Wb, binter, decay);
  k_intra<<<dim3(16, 4, 4), 512, 0, stream>>>(out_bf, vT, binter, reads, decay);
  k_final<<<dim3(4, 256), 256, 0, stream>>>(reads, wrd_bf, out_f, outp);
}

// Round 17
// 263.877 us; speedup vs baseline: 1.0200x; 1.0200x over previous
//
#include <hip/hip_runtime.h>

#define Bn 4
#define Tn 8192
#define Dn 512
#define GC 512
#define NG 16
#define ALPHAc 0.03f

typedef unsigned short u16;
typedef short bf8_t __attribute__((ext_vector_type(8)));
typedef float f4_t  __attribute__((ext_vector_type(4)));
typedef u16 us8_t __attribute__((ext_vector_type(8)));
typedef u16 us4_t __attribute__((ext_vector_type(4)));

#define MFMA16(a,b,c) __builtin_amdgcn_mfma_f32_16x16x32_bf16((a),(b),(c),0,0,0)

__device__ __forceinline__ u16 f2bf(float f) {
  union { float f; unsigned u; } v; v.f = f;
  unsigned r = v.u + 0x7fffu + ((v.u >> 16) & 1u);
  return (u16)(r >> 16);
}
__device__ __forceinline__ float bf2f(u16 h) {
  union { unsigned u; float f; } v; v.u = ((unsigned)h) << 16;
  return v.f;
}
// async global->LDS, 16B per lane; LDS dest wave-uniform base (HW adds lane*16)
__device__ __forceinline__ void gload_lds16(const u16* g, u16* l) {
  __builtin_amdgcn_global_load_lds(
      (const __attribute__((address_space(1))) void*)g,
      (__attribute__((address_space(3))) void*)l, 16, 0, 0);
}

// ---------------- fp32 -> bf16 convert ----------------
__global__ __launch_bounds__(256) void k_convert(const float* __restrict__ src,
                                                 u16* __restrict__ dst, int n4) {
  int i = blockIdx.x * 256 + threadIdx.x;
  if (i >= n4) return;
  float4 v = ((const float4*)src)[i];
  us4_t o = { f2bf(v.x), f2bf(v.y), f2bf(v.z), f2bf(v.w) };
  ((us4_t*)dst)[i] = o;
}

// ---------------- transpose+shift+SCALE: wkTg[b][e][t] = out[b,t-1,e] * gw(t) ----------------
// gw(t) = gamma^(GC-1 - t%GC). wkTg consumed ONLY by k_gemm_u (scale folded here).
__global__ __launch_bounds__(256) void k_wkT(const u16* __restrict__ src,
                                             u16* __restrict__ dst,
                                             const float* __restrict__ decay) {
  __shared__ u16 T[128*129];
  const int tid = threadIdx.x;
  const int t0 = blockIdx.x * 128, e0 = blockIdx.y * 128;
  const int b = blockIdx.z;
  const size_t bT = (size_t)b * Tn;
  const float gamma = 1.f / (1.f + __builtin_expf(-decay[0]));
  const float l2g = __builtin_log2f(gamma);
#pragma unroll
  for (int i = 0; i < 8; ++i) {
    int slot = i*256 + tid;
    int row = slot >> 4, c8 = (slot & 15) << 3;
    int tg = t0 + row - 1;
    us8_t v8 = {0,0,0,0,0,0,0,0};
    if (tg >= 0) v8 = *(const us8_t*)&src[(bT + tg)*Dn + e0 + c8];
    const float gw = __builtin_exp2f(l2g * (float)(GC - 1 - ((t0 + row) & (GC - 1))));
#pragma unroll
    for (int k = 0; k < 8; ++k) T[row*129 + c8 + k] = f2bf(bf2f(v8[k]) * gw);
  }
  __syncthreads();
#pragma unroll
  for (int i = 0; i < 8; ++i) {
    int slot = i*256 + tid;
    int e = slot >> 4, t8 = (slot & 15) << 3;
    us8_t o;
#pragma unroll
    for (int k = 0; k < 8; ++k) o[k] = T[(t8 + k)*129 + e];
    *(us8_t*)&dst[((size_t)b*Dn + e0 + e)*Tn + t0 + t8] = o;
  }
}

// ---------------- K1: vT = (out @ w_write^T)^T, m97-style staged ----------------
__global__ __launch_bounds__(256) void k_gemm_v(const u16* __restrict__ A,
                                                const u16* __restrict__ Bm,
                                                u16* __restrict__ vT) {
  __shared__ u16 lds[128*136];
  u16* As = lds;
  u16* Bs = lds + 128*64;
  const int tid = threadIdx.x;
  const int lane = tid & 63, w = tid >> 6;
  const int g = lane >> 4, lr = lane & 15;
  const int rl = lane >> 3, cb = (lane & 7) * 8;
  const int m0 = blockIdx.y * 128, n0 = blockIdx.x * 128;
  const int wm = (w >> 1) * 64, wn = (w & 1) * 64;
  f4_t acc[4][4];
#pragma unroll
  for (int i = 0; i < 4; ++i)
#pragma unroll
    for (int j = 0; j < 4; ++j) acc[i][j] = (f4_t){0.f, 0.f, 0.f, 0.f};

  for (int kb = 0; kb < 8; ++kb) {
    const int k0 = kb * 64;
    __syncthreads();
#pragma unroll
    for (int i = 0; i < 4; ++i) {
      int r0 = (w*4 + i) * 8;
      gload_lds16(&A[(size_t)(m0 + r0 + rl)*Dn + k0 + cb], &As[r0*64]);
      gload_lds16(&Bm[(size_t)(n0 + r0 + rl)*Dn + k0 + cb], &Bs[r0*64]);
    }
    __syncthreads();
#pragma unroll
    for (int kk = 0; kk < 2; ++kk) {
      const int co = kk*32 + g*8;
      bf8_t a[4], b[4];
#pragma unroll
      for (int mf = 0; mf < 4; ++mf) a[mf] = *(const bf8_t*)&As[(wm + mf*16 + lr)*64 + co];
#pragma unroll
      for (int nf = 0; nf < 4; ++nf) b[nf] = *(const bf8_t*)&Bs[(wn + nf*16 + lr)*64 + co];
#pragma unroll
      for (int mf = 0; mf < 4; ++mf)
#pragma unroll
        for (int nf = 0; nf < 4; ++nf)
          acc[mf][nf] = MFMA16(a[mf], b[nf], acc[mf][nf]);
    }
  }
  __syncthreads();
  u16* Cs = lds;  // [128 d][136 t]
#pragma unroll
  for (int mf = 0; mf < 4; ++mf)
#pragma unroll
    for (int nf = 0; nf < 4; ++nf)
#pragma unroll
      for (int r = 0; r < 4; ++r)
        Cs[(wn + nf*16 + lr)*136 + (wm + mf*16 + g*4 + r)] = f2bf(acc[mf][nf][r]);
  __syncthreads();
  const int b = m0 >> 13;
  const int tt0 = m0 & 8191;
#pragma unroll
  for (int i = 0; i < 8; ++i) {
    int slot = i * 256 + tid;
    int d = slot >> 4, t8 = (slot & 15) << 3;
    *(us8_t*)&vT[((size_t)b*Dn + n0 + d)*Tn + tt0 + t8] = *(const us8_t*)&Cs[d*136 + t8];
  }
}

// ---------------- K2: U_g[d][e] = sum_t vT[d][t]*wkTg[e][t], m97-style staged ----------------
__global__ __launch_bounds__(256) void k_gemm_u(const u16* __restrict__ vT,
                                                const u16* __restrict__ wkTg,
                                                u16* __restrict__ U) {
  __shared__ u16 lds[128*64*2];
  u16* As = lds;
  u16* Bs = lds + 128*64;
  const int tid = threadIdx.x;
  const int lane = tid & 63, w = tid >> 6;
  const int g = lane >> 4, lr = lane & 15;
  const int rl = lane >> 3, cb = (lane & 7) * 8;
  const int d0 = blockIdx.y * 128, e0 = blockIdx.x * 128;
  const int bg = blockIdx.z;
  const int b = bg >> 4, gg = bg & 15;
  const int wm = (w >> 1) * 64, wn = (w & 1) * 64;
  const size_t kbase = (size_t)gg * GC;
  f4_t acc[4][4];
#pragma unroll
  for (int i = 0; i < 4; ++i)
#pragma unroll
    for (int j = 0; j < 4; ++j) acc[i][j] = (f4_t){0.f, 0.f, 0.f, 0.f};

  for (int kb = 0; kb < 8; ++kb) {
    const int k0 = kb * 64;
    __syncthreads();
#pragma unroll
    for (int i = 0; i < 4; ++i) {
      int r0 = (w*4 + i) * 8;
      gload_lds16(&vT[((size_t)b*Dn + d0 + r0 + rl)*Tn + kbase + k0 + cb], &As[r0*64]);
      gload_lds16(&wkTg[((size_t)b*Dn + e0 + r0 + rl)*Tn + kbase + k0 + cb], &Bs[r0*64]);
    }
    __syncthreads();
#pragma unroll
    for (int kk = 0; kk < 2; ++kk) {
      const int co = kk*32 + g*8;
      bf8_t a[4], bb[4];
#pragma unroll
      for (int mf = 0; mf < 4; ++mf) a[mf] = *(const bf8_t*)&As[(wm + mf*16 + lr)*64 + co];
#pragma unroll
      for (int nf = 0; nf < 4; ++nf) bb[nf] = *(const bf8_t*)&Bs[(wn + nf*16 + lr)*64 + co];
#pragma unroll
      for (int mf = 0; mf < 4; ++mf)
#pragma unroll
        for (int nf = 0; nf < 4; ++nf)
          acc[mf][nf] = MFMA16(a[mf], bb[nf], acc[mf][nf]);
    }
  }
  const size_t ub = (size_t)bg * Dn * Dn;
#pragma unroll
  for (int mf = 0; mf < 4; ++mf)
#pragma unroll
    for (int nf = 0; nf < 4; ++nf)
#pragma unroll
      for (int r = 0; r < 4; ++r)
        U[ub + (size_t)(d0 + wm + mf*16 + g*4 + r)*Dn + e0 + wn + nf*16 + lr] = f2bf(acc[mf][nf][r]);
}

// ---------------- K3: 16-step scan over chunk totals -> Wb[b][g] (bf16, pre-update) ----------------
__global__ __launch_bounds__(256) void k_bscan(const u16* __restrict__ U,
                                               u16* __restrict__ Wb,
                                               const float* __restrict__ decay) {
  const int tid = threadIdx.x;
  const int d0 = blockIdx.x * 64, e0 = blockIdx.y * 64;
  const int b = blockIdx.z;
  const float gamma = 1.f / (1.f + __builtin_expf(-decay[0]));
  const float gCC = __builtin_exp2f(__builtin_log2f(gamma) * (float)GC);
  const int colb = (tid & 15) << 2;
  const int rowb = (tid >> 4) << 2;
  float st[4][4];
#pragma unroll
  for (int rr = 0; rr < 4; ++rr)
#pragma unroll
    for (int cc = 0; cc < 4; ++cc) st[rr][cc] = 0.f;

  for (int gg = 0; gg < NG; ++gg) {
    const size_t base = (size_t)(b*NG + gg) * Dn * Dn;
#pragma unroll
    for (int rr = 0; rr < 4; ++rr) {
      us4_t o = { f2bf(st[rr][0]), f2bf(st[rr][1]), f2bf(st[rr][2]), f2bf(st[rr][3]) };
      *(us4_t*)&Wb[base + (size_t)(d0 + rowb + rr)*Dn + e0 + colb] = o;
      us4_t u4 = *(const us4_t*)&U[base + (size_t)(d0 + rowb + rr)*Dn + e0 + colb];
      st[rr][0] = gCC*st[rr][0] + bf2f(u4.x);
      st[rr][1] = gCC*st[rr][1] + bf2f(u4.y);
      st[rr][2] = gCC*st[rr][2] + bf2f(u4.z);
      st[rr][3] = gCC*st[rr][3] + bf2f(u4.w);
    }
  }
}

// ---------------- K4: binter = gamma^{tloc} * rk_g @ Wb_g^T, m97-style staged ----------------
__global__ __launch_bounds__(256) void k_binter(const u16* __restrict__ out_bf,
                                                const u16* __restrict__ Wb,
                                                u16* __restrict__ binter,
                                                const float* __restrict__ decay) {
  __shared__ u16 lds[128*136];
  u16* As = lds;
  u16* Bs = lds + 128*64;
  const int tid = threadIdx.x;
  const int lane = tid & 63, w = tid >> 6;
  const int g = lane >> 4, lr = lane & 15;
  const int rl = lane >> 3, cb = (lane & 7) * 8;
  const int m0 = blockIdx.y * 128, n0 = blockIdx.x * 128;
  const int z = blockIdx.z;
  const int b = z / 15, gg = z % 15 + 1;
  const int wm = (w >> 1) * 64, wn = (w & 1) * 64;
  const float gamma = 1.f / (1.f + __builtin_expf(-decay[0]));
  const float l2g = __builtin_log2f(gamma);
  const size_t arow = (size_t)b*Tn + (size_t)gg*GC + m0;
  const size_t brow = (size_t)(b*NG + gg) * Dn * Dn;
  f4_t acc[4][4];
#pragma unroll
  for (int i = 0; i < 4; ++i)
#pragma unroll
    for (int j = 0; j < 4; ++j) acc[i][j] = (f4_t){0.f, 0.f, 0.f, 0.f};

  for (int kb = 0; kb < 8; ++kb) {
    const int k0 = kb * 64;
    __syncthreads();
#pragma unroll
    for (int i = 0; i < 4; ++i) {
      int r0 = (w*4 + i) * 8;
      gload_lds16(&out_bf[(arow + r0 + rl)*Dn + k0 + cb], &As[r0*64]);
      gload_lds16(&Wb[brow + (size_t)(n0 + r0 + rl)*Dn + k0 + cb], &Bs[r0*64]);
    }
    __syncthreads();
#pragma unroll
    for (int kk = 0; kk < 2; ++kk) {
      const int co = kk*32 + g*8;
      bf8_t a[4], bb[4];
#pragma unroll
      for (int mf = 0; mf < 4; ++mf) a[mf] = *(const bf8_t*)&As[(wm + mf*16 + lr)*64 + co];
#pragma unroll
      for (int nf = 0; nf < 4; ++nf) bb[nf] = *(const bf8_t*)&Bs[(wn + nf*16 + lr)*64 + co];
#pragma unroll
      for (int mf = 0; mf < 4; ++mf)
#pragma unroll
        for (int nf = 0; nf < 4; ++nf)
          acc[mf][nf] = MFMA16(a[mf], bb[nf], acc[mf][nf]);
    }
  }
  __syncthreads();
  u16* Cs = lds;  // [128 t][136 d]
#pragma unroll
  for (int mf = 0; mf < 4; ++mf) {
#pragma unroll
    for (int r = 0; r < 4; ++r) {
      const float gp = __builtin_exp2f(l2g * (float)(m0 + wm + mf*16 + g*4 + r));
#pragma unroll
      for (int nf = 0; nf < 4; ++nf)
        Cs[(wm + mf*16 + g*4 + r)*136 + wn + nf*16 + lr] = f2bf(acc[mf][nf][r] * gp);
    }
  }
  __syncthreads();
#pragma unroll
  for (int i = 0; i < 8; ++i) {
    int slot = i * 256 + tid;
    int r = slot >> 4, c8 = (slot & 15) << 3;
    *(us8_t*)&binter[(arow + r)*Dn + n0 + c8] = *(const us8_t*)&Cs[r*136 + c8];
  }
}

// ---------------- K5: intra v9 — v6 + exp2-free mask + epilogue binter prefetch ----------------
// grid (16 gg, 4 qt2, 4 b) x 512 thr. LDS 151,552 B (1 WG/CU, 2 waves/SIMD).
__global__ __launch_bounds__(512, 2) void k_intra(const u16* __restrict__ out_bf,
                                                  const u16* __restrict__ vT,
                                                  const u16* __restrict__ binter,
                                                  u16* __restrict__ reads_bf,
                                                  const float* __restrict__ decay) {
  __shared__ u16 WK2[2*64*520];   // wk double-buffer [p][s 64][e 512 (+8 pad)]
  __shared__ u16 PS[128*72];      // P [t 128][s 64 (+8 pad)]
  const int tid = threadIdx.x;
  const int lane = tid & 63, w = tid >> 6;   // 8 waves
  const int g = lane >> 4, lr = lane & 15;
  const int gg = blockIdx.x, qt2 = blockIdx.y, b = blockIdx.z;
  const int jmax = 2*qt2 + 2;
  const float gamma = 1.f / (1.f + __builtin_expf(-decay[0]));
  const float l2g = __builtin_log2f(gamma);
  const size_t bT = (size_t)b * Tn;
  const size_t tbase = bT + (size_t)gg*GC + qt2*128;

  // QKT A-operand: wave w owns t-strip w*16; rk row in regs, loaded once
  bf8_t rk[16];
#pragma unroll
  for (int kk = 0; kk < 16; ++kk)
    rk[kk] = *(const bf8_t*)&out_bf[(tbase + w*16 + lr)*Dn + kk*32 + g*8];

  // PV A-operand base: d row = w*64 + mf*16 + lr (XCD-L2-local via gg swizzle)
  const u16* vbase = vT + ((size_t)b*Dn + w*64 + lr)*Tn + (size_t)gg*GC + g*8;

  // mask factors: gamma^(dd-1) = cj * gt[r] * gs[nf] (exp2-free inner loop)
  float gt[4], gs[4];
#pragma unroll
  for (int r = 0; r < 4; ++r)
    gt[r] = __builtin_exp2f(l2g * (float)(w*16 + g*4 + r));
#pragma unroll
  for (int nf = 0; nf < 4; ++nf)
    gs[nf] = __builtin_exp2f(-l2g * (float)(nf*16 + lr));

  f4_t acc[4][8];   // [mf: d 64][nf: t 128]
#pragma unroll
  for (int i = 0; i < 4; ++i)
#pragma unroll
    for (int j = 0; j < 8; ++j) acc[i][j] = (f4_t){0.f, 0.f, 0.f, 0.f};

#define STAGE_J(JJ, P)                                                        \
  {                                                                           \
    const int sgs = gg*GC + (JJ)*64;                                          \
    u16* sbase = &WK2[(P)*64*520];                                            \
    _Pragma("unroll")                                                         \
    for (int i = 0; i < 8; ++i) {                                             \
      int row = i*8 + w;                                                      \
      int wr = sgs + row - 1;                                                 \
      if (wr < 0) wr = 0;  /* only (gg==0,j==0,row==0); zero-fixed below */   \
      gload_lds16(&out_bf[(bT + (size_t)wr)*Dn + lane*8], &sbase[row*520]);   \
    }                                                                         \
  }

  STAGE_J(0, 0);
  __syncthreads();                 // drain stage(0)
  if (gg == 0 && tid < 64) {       // global t=0: wk row is zero
    us8_t z = {0,0,0,0,0,0,0,0};
    *(us8_t*)&WK2[tid*8] = z;
  }
  __syncthreads();

  for (int j = 0; j < jmax; ++j) {
    const int p = j & 1;
    if (j + 1 < jmax) STAGE_J(j + 1, p ^ 1);   // async prefetch, drains at (B)
    const u16* buf = &WK2[p*64*520];
    f4_t sacc[4];
#pragma unroll
    for (int i = 0; i < 4; ++i) sacc[i] = (f4_t){0.f, 0.f, 0.f, 0.f};
#pragma unroll
    for (int kk = 0; kk < 16; ++kk) {
      const int co = kk*32 + g*8;
#pragma unroll
      for (int nf = 0; nf < 4; ++nf) {
        bf8_t bb = *(const bf8_t*)&buf[(nf*16 + lr)*520 + co];
        sacc[nf] = MFMA16(rk[kk], bb, sacc[nf]);
      }
    }
    // mask+decay -> PS[t][s]; thread holds tt = w*16+g*4+r, ss = nf*16+lr
    const int off = qt2*128 - j*64;
    const float cj = __builtin_exp2f(l2g * (float)(off - 1));
#pragma unroll
    for (int nf = 0; nf < 4; ++nf) {
      const float cn = cj * gs[nf];
#pragma unroll
      for (int r = 0; r < 4; ++r) {
        const int tt = w*16 + g*4 + r;
        const int ss = nf*16 + lr;
        const int dd = off + tt - ss;
        float mval = (dd > 0) ? (cn * gt[r]) : 0.f;
        PS[tt*72 + ss] = f2bf(sacc[nf][r] * mval);
      }
    }
    __syncthreads();   // (B): PS visible; stage(j+1) drained
    // PV: acc[d][t] += vT x P over this s-block
#pragma unroll
    for (int kk = 0; kk < 2; ++kk) {
      const int co = kk*32 + g*8;
      bf8_t a[4], bb[8];
#pragma unroll
      for (int mf = 0; mf < 4; ++mf)
        a[mf] = *(const bf8_t*)(vbase + (size_t)(mf*16)*Tn + j*64 + kk*32);
#pragma unroll
      for (int nf = 0; nf < 8; ++nf) bb[nf] = *(const bf8_t*)&PS[(nf*16 + lr)*72 + co];
#pragma unroll
      for (int mf = 0; mf < 4; ++mf)
#pragma unroll
        for (int nf = 0; nf < 8; ++nf)
          acc[mf][nf] = MFMA16(a[mf], bb[nf], acc[mf][nf]);
    }
    __syncthreads();   // (A'): PV done with PS; buf p free for stage(j+2)
  }
#undef STAGE_J

  // epilogue: two d-half passes via EP = WK2 [128 t][264]; binter prefetched to regs
  u16* EP = WK2;
#pragma unroll
  for (int pp = 0; pp < 2; ++pp) {
    us8_t bv[8];
    if (gg > 0) {
#pragma unroll
      for (int i = 0; i < 8; ++i) {
        int slot = i*512 + tid;
        int t = slot >> 5, d8 = (slot & 31) << 3;
        bv[i] = *(const us8_t*)&binter[(tbase + t)*Dn + pp*256 + d8];
      }
    }
    __syncthreads();
    if ((w >> 2) == pp) {
      const int wq = w & 3;
#pragma unroll
      for (int mf = 0; mf < 4; ++mf)
#pragma unroll
        for (int nf = 0; nf < 8; ++nf)
#pragma unroll
          for (int r = 0; r < 4; ++r)
            EP[(nf*16 + lr)*264 + wq*64 + mf*16 + g*4 + r] = f2bf(acc[mf][nf][r]);
    }
    __syncthreads();
#pragma unroll
    for (int i = 0; i < 8; ++i) {
      int slot = i*512 + tid;
      int t = slot >> 5, d8 = (slot & 31) << 3;
      us8_t ev = *(const us8_t*)&EP[t*264 + d8];
      us8_t o;
      if (gg > 0) {
#pragma unroll
        for (int k = 0; k < 8; ++k) o[k] = f2bf(bf2f(ev[k]) + bf2f(bv[i][k]));
      } else {
        o = ev;
      }
      *(us8_t*)&reads_bf[(tbase + t)*Dn + pp*256 + d8] = o;
    }
  }
}

// ---------------- K6: out = resid + alpha * (reads @ w_read^T), m97-style staged ----------------
__global__ __launch_bounds__(256) void k_final(const u16* __restrict__ A,
                                               const u16* __restrict__ Bm,
                                               const float* __restrict__ resid,
                                               float* __restrict__ Cout) {
  __shared__ u16 lds[128*64*2];
  u16* As = lds;
  u16* Bs = lds + 128*64;
  const int tid = threadIdx.x;
  const int lane = tid & 63, w = tid >> 6;
  const int g = lane >> 4, lr = lane & 15;
  const int rl = lane >> 3, cb = (lane & 7) * 8;
  const int m0 = blockIdx.y * 128, n0 = blockIdx.x * 128;
  const int wm = (w >> 1) * 64, wn = (w & 1) * 64;
  f4_t acc[4][4];
#pragma unroll
  for (int i = 0; i < 4; ++i)
#pragma unroll
    for (int j = 0; j < 4; ++j) acc[i][j] = (f4_t){0.f, 0.f, 0.f, 0.f};

  for (int kb = 0; kb < 8; ++kb) {
    const int k0 = kb * 64;
    __syncthreads();
#pragma unroll
    for (int i = 0; i < 4; ++i) {
      int r0 = (w*4 + i) * 8;
      gload_lds16(&A[(size_t)(m0 + r0 + rl)*Dn + k0 + cb], &As[r0*64]);
      gload_lds16(&Bm[(size_t)(n0 + r0 + rl)*Dn + k0 + cb], &Bs[r0*64]);
    }
    __syncthreads();
#pragma unroll
    for (int kk = 0; kk < 2; ++kk) {
      const int co = kk*32 + g*8;
      bf8_t a[4], b[4];
#pragma unroll
      for (int mf = 0; mf < 4; ++mf) a[mf] = *(const bf8_t*)&As[(wm + mf*16 + lr)*64 + co];
#pragma unroll
      for (int nf = 0; nf < 4; ++nf) b[nf] = *(const bf8_t*)&Bs[(wn + nf*16 + lr)*64 + co];
#pragma unroll
      for (int mf = 0; mf < 4; ++mf)
#pragma unroll
        for (int nf = 0; nf < 4; ++nf)
          acc[mf][nf] = MFMA16(a[mf], b[nf], acc[mf][nf]);
    }
  }
#pragma unroll
  for (int mf = 0; mf < 4; ++mf)
#pragma unroll
    for (int nf = 0; nf < 4; ++nf)
#pragma unroll
      for (int r = 0; r < 4; ++r) {
        int row = m0 + wm + mf*16 + g*4 + r;
        int col = n0 + wn + nf*16 + lr;
        int idx = row * Dn + col;
        Cout[idx] = resid[idx] + ALPHAc * acc[mf][nf][r];
      }
}

extern "C" void kernel_launch(void* const* d_in, const int* in_sizes, int n_in,
                              void* d_out, int out_size, void* d_ws, size_t ws_size,
                              hipStream_t stream) {
  const float* out_f   = (const float*)d_in[0];
  const float* w_write = (const float*)d_in[1];
  const float* w_read  = (const float*)d_in[2];
  const float* decay   = (const float*)d_in[3];
  float* outp = (float*)d_out;

  char* ws = (char*)d_ws;
  // NON-ALIASED layout (replay-overlap safe). Total 235,929,600 B.
  u16*   out_bf = (u16*)(ws);
  u16*   wkTg   = (u16*)(ws + (size_t)33554432);
  u16*   vT     = (u16*)(ws + (size_t)67108864);
  u16*   wwt_bf = (u16*)(ws + (size_t)100663296);
  u16*   wrd_bf = (u16*)(ws + (size_t)101187584);
  u16*   U      = (u16*)(ws + (size_t)101711872);
  u16*   binter = (u16*)(ws + (size_t)135266304);
  u16*   reads  = (u16*)(ws + (size_t)168820736);
  u16*   Wb     = (u16*)(ws + (size_t)202375168);

  k_convert<<<16384, 256, 0, stream>>>(out_f, out_bf, 4194304);
  k_convert<<<256, 256, 0, stream>>>(w_write, wwt_bf, 65536);
  k_convert<<<256, 256, 0, stream>>>(w_read, wrd_bf, 65536);
  k_wkT<<<dim3(64, 4, 4), 256, 0, stream>>>(out_bf, wkTg, decay);
  k_gemm_v<<<dim3(4, 256), 256, 0, stream>>>(out_bf, wwt_bf, vT);
  k_gemm_u<<<dim3(4, 4, 64), 256, 0, stream>>>(vT, wkTg, U);
  k_bscan<<<dim3(8, 8, 4), 256, 0, stream>>>(U, Wb, decay);
  k_binter<<<dim3(4, 4, 60), 256, 0, stream>>>(out_bf, Wb, binter, decay);
  k_intra<<<dim3(16, 4, 4), 512, 0, stream>>>(out_bf, vT, binter, reads, decay);
  k_final<<<dim3(4, 256), 256, 0, stream>>>(reads, wrd_bf, out_f, outp);
}

// Round 18
// 261.693 us; speedup vs baseline: 1.0285x; 1.0083x over previous
//
#include <hip/hip_runtime.h>

#define Bn 4
#define Tn 8192
#define Dn 512
#define GC 512
#define NG 16
#define ALPHAc 0.03f

typedef unsigned short u16;
typedef short bf8_t __attribute__((ext_vector_type(8)));
typedef float f4_t  __attribute__((ext_vector_type(4)));
typedef u16 us8_t __attribute__((ext_vector_type(8)));
typedef u16 us4_t __attribute__((ext_vector_type(4)));

#define MFMA16(a,b,c) __builtin_amdgcn_mfma_f32_16x16x32_bf16((a),(b),(c),0,0,0)

__device__ __forceinline__ u16 f2bf(float f) {
  union { float f; unsigned u; } v; v.f = f;
  unsigned r = v.u + 0x7fffu + ((v.u >> 16) & 1u);
  return (u16)(r >> 16);
}
__device__ __forceinline__ float bf2f(u16 h) {
  union { unsigned u; float f; } v; v.u = ((unsigned)h) << 16;
  return v.f;
}
// async global->LDS, 16B per lane; LDS dest wave-uniform base (HW adds lane*16)
__device__ __forceinline__ void gload_lds16(const u16* g, u16* l) {
  __builtin_amdgcn_global_load_lds(
      (const __attribute__((address_space(1))) void*)g,
      (__attribute__((address_space(3))) void*)l, 16, 0, 0);
}

// ---------------- fused fp32 -> bf16 convert (out | w_write | w_read) ----------------
__global__ __launch_bounds__(256) void k_convert3(const float* __restrict__ s0,
                                                  const float* __restrict__ s1,
                                                  const float* __restrict__ s2,
                                                  u16* __restrict__ d0,
                                                  u16* __restrict__ d1,
                                                  u16* __restrict__ d2) {
  int i = blockIdx.x * 256 + threadIdx.x;
  const float* s; u16* d; int off;
  if (i < 4194304)      { s = s0; d = d0; off = i; }
  else if (i < 4259840) { s = s1; d = d1; off = i - 4194304; }
  else                  { s = s2; d = d2; off = i - 4259840; }
  float4 v = ((const float4*)s)[off];
  us4_t o = { f2bf(v.x), f2bf(v.y), f2bf(v.z), f2bf(v.w) };
  ((us4_t*)d)[off] = o;
}

// ---------------- transpose+shift+SCALE: wkTg[b][e][t] = out[b,t-1,e] * gw(t) ----------------
__global__ __launch_bounds__(256) void k_wkT(const u16* __restrict__ src,
                                             u16* __restrict__ dst,
                                             const float* __restrict__ decay) {
  __shared__ u16 T[128*129];
  const int tid = threadIdx.x;
  const int t0 = blockIdx.x * 128, e0 = blockIdx.y * 128;
  const int b = blockIdx.z;
  const size_t bT = (size_t)b * Tn;
  const float gamma = 1.f / (1.f + __builtin_expf(-decay[0]));
  const float l2g = __builtin_log2f(gamma);
#pragma unroll
  for (int i = 0; i < 8; ++i) {
    int slot = i*256 + tid;
    int row = slot >> 4, c8 = (slot & 15) << 3;
    int tg = t0 + row - 1;
    us8_t v8 = {0,0,0,0,0,0,0,0};
    if (tg >= 0) v8 = *(const us8_t*)&src[(bT + tg)*Dn + e0 + c8];
    const float gw = __builtin_exp2f(l2g * (float)(GC - 1 - ((t0 + row) & (GC - 1))));
#pragma unroll
    for (int k = 0; k < 8; ++k) T[row*129 + c8 + k] = f2bf(bf2f(v8[k]) * gw);
  }
  __syncthreads();
#pragma unroll
  for (int i = 0; i < 8; ++i) {
    int slot = i*256 + tid;
    int e = slot >> 4, t8 = (slot & 15) << 3;
    us8_t o;
#pragma unroll
    for (int k = 0; k < 8; ++k) o[k] = T[(t8 + k)*129 + e];
    *(us8_t*)&dst[((size_t)b*Dn + e0 + e)*Tn + t0 + t8] = o;
  }
}

// ---------------- K1: vT = (out @ w_write^T)^T, m97-style staged ----------------
__global__ __launch_bounds__(256) void k_gemm_v(const u16* __restrict__ A,
                                                const u16* __restrict__ Bm,
                                                u16* __restrict__ vT) {
  __shared__ u16 lds[128*136];
  u16* As = lds;
  u16* Bs = lds + 128*64;
  const int tid = threadIdx.x;
  const int lane = tid & 63, w = tid >> 6;
  const int g = lane >> 4, lr = lane & 15;
  const int rl = lane >> 3, cb = (lane & 7) * 8;
  const int m0 = blockIdx.y * 128, n0 = blockIdx.x * 128;
  const int wm = (w >> 1) * 64, wn = (w & 1) * 64;
  f4_t acc[4][4];
#pragma unroll
  for (int i = 0; i < 4; ++i)
#pragma unroll
    for (int j = 0; j < 4; ++j) acc[i][j] = (f4_t){0.f, 0.f, 0.f, 0.f};

  for (int kb = 0; kb < 8; ++kb) {
    const int k0 = kb * 64;
    __syncthreads();
#pragma unroll
    for (int i = 0; i < 4; ++i) {
      int r0 = (w*4 + i) * 8;
      gload_lds16(&A[(size_t)(m0 + r0 + rl)*Dn + k0 + cb], &As[r0*64]);
      gload_lds16(&Bm[(size_t)(n0 + r0 + rl)*Dn + k0 + cb], &Bs[r0*64]);
    }
    __syncthreads();
#pragma unroll
    for (int kk = 0; kk < 2; ++kk) {
      const int co = kk*32 + g*8;
      bf8_t a[4], b[4];
#pragma unroll
      for (int mf = 0; mf < 4; ++mf) a[mf] = *(const bf8_t*)&As[(wm + mf*16 + lr)*64 + co];
#pragma unroll
      for (int nf = 0; nf < 4; ++nf) b[nf] = *(const bf8_t*)&Bs[(wn + nf*16 + lr)*64 + co];
#pragma unroll
      for (int mf = 0; mf < 4; ++mf)
#pragma unroll
        for (int nf = 0; nf < 4; ++nf)
          acc[mf][nf] = MFMA16(a[mf], b[nf], acc[mf][nf]);
    }
  }
  __syncthreads();
  u16* Cs = lds;  // [128 d][136 t]
#pragma unroll
  for (int mf = 0; mf < 4; ++mf)
#pragma unroll
    for (int nf = 0; nf < 4; ++nf)
#pragma unroll
      for (int r = 0; r < 4; ++r)
        Cs[(wn + nf*16 + lr)*136 + (wm + mf*16 + g*4 + r)] = f2bf(acc[mf][nf][r]);
  __syncthreads();
  const int b = m0 >> 13;
  const int tt0 = m0 & 8191;
#pragma unroll
  for (int i = 0; i < 8; ++i) {
    int slot = i * 256 + tid;
    int d = slot >> 4, t8 = (slot & 15) << 3;
    *(us8_t*)&vT[((size_t)b*Dn + n0 + d)*Tn + tt0 + t8] = *(const us8_t*)&Cs[d*136 + t8];
  }
}

// ---------------- K2: U_g[d][e] = sum_t vT[d][t]*wkTg[e][t], m97-style staged ----------------
__global__ __launch_bounds__(256) void k_gemm_u(const u16* __restrict__ vT,
                                                const u16* __restrict__ wkTg,
                                                u16* __restrict__ U) {
  __shared__ u16 lds[128*64*2];
  u16* As = lds;
  u16* Bs = lds + 128*64;
  const int tid = threadIdx.x;
  const int lane = tid & 63, w = tid >> 6;
  const int g = lane >> 4, lr = lane & 15;
  const int rl = lane >> 3, cb = (lane & 7) * 8;
  const int d0 = blockIdx.y * 128, e0 = blockIdx.x * 128;
  const int bg = blockIdx.z;
  const int b = bg >> 4, gg = bg & 15;
  const int wm = (w >> 1) * 64, wn = (w & 1) * 64;
  const size_t kbase = (size_t)gg * GC;
  f4_t acc[4][4];
#pragma unroll
  for (int i = 0; i < 4; ++i)
#pragma unroll
    for (int j = 0; j < 4; ++j) acc[i][j] = (f4_t){0.f, 0.f, 0.f, 0.f};

  for (int kb = 0; kb < 8; ++kb) {
    const int k0 = kb * 64;
    __syncthreads();
#pragma unroll
    for (int i = 0; i < 4; ++i) {
      int r0 = (w*4 + i) * 8;
      gload_lds16(&vT[((size_t)b*Dn + d0 + r0 + rl)*Tn + kbase + k0 + cb], &As[r0*64]);
      gload_lds16(&wkTg[((size_t)b*Dn + e0 + r0 + rl)*Tn + kbase + k0 + cb], &Bs[r0*64]);
    }
    __syncthreads();
#pragma unroll
    for (int kk = 0; kk < 2; ++kk) {
      const int co = kk*32 + g*8;
      bf8_t a[4], bb[4];
#pragma unroll
      for (int mf = 0; mf < 4; ++mf) a[mf] = *(const bf8_t*)&As[(wm + mf*16 + lr)*64 + co];
#pragma unroll
      for (int nf = 0; nf < 4; ++nf) bb[nf] = *(const bf8_t*)&Bs[(wn + nf*16 + lr)*64 + co];
#pragma unroll
      for (int mf = 0; mf < 4; ++mf)
#pragma unroll
        for (int nf = 0; nf < 4; ++nf)
          acc[mf][nf] = MFMA16(a[mf], bb[nf], acc[mf][nf]);
    }
  }
  const size_t ub = (size_t)bg * Dn * Dn;
#pragma unroll
  for (int mf = 0; mf < 4; ++mf)
#pragma unroll
    for (int nf = 0; nf < 4; ++nf)
#pragma unroll
      for (int r = 0; r < 4; ++r)
        U[ub + (size_t)(d0 + wm + mf*16 + g*4 + r)*Dn + e0 + wn + nf*16 + lr] = f2bf(acc[mf][nf][r]);
}

// ---------------- K3: 16-step scan over chunk totals -> Wb[b][g] (bf16, pre-update) ----------------
__global__ __launch_bounds__(256) void k_bscan(const u16* __restrict__ U,
                                               u16* __restrict__ Wb,
                                               const float* __restrict__ decay) {
  const int tid = threadIdx.x;
  const int d0 = blockIdx.x * 64, e0 = blockIdx.y * 64;
  const int b = blockIdx.z;
  const float gamma = 1.f / (1.f + __builtin_expf(-decay[0]));
  const float gCC = __builtin_exp2f(__builtin_log2f(gamma) * (float)GC);
  const int colb = (tid & 15) << 2;
  const int rowb = (tid >> 4) << 2;
  float st[4][4];
#pragma unroll
  for (int rr = 0; rr < 4; ++rr)
#pragma unroll
    for (int cc = 0; cc < 4; ++cc) st[rr][cc] = 0.f;

  for (int gg = 0; gg < NG; ++gg) {
    const size_t base = (size_t)(b*NG + gg) * Dn * Dn;
#pragma unroll
    for (int rr = 0; rr < 4; ++rr) {
      us4_t o = { f2bf(st[rr][0]), f2bf(st[rr][1]), f2bf(st[rr][2]), f2bf(st[rr][3]) };
      *(us4_t*)&Wb[base + (size_t)(d0 + rowb + rr)*Dn + e0 + colb] = o;
      us4_t u4 = *(const us4_t*)&U[base + (size_t)(d0 + rowb + rr)*Dn + e0 + colb];
      st[rr][0] = gCC*st[rr][0] + bf2f(u4.x);
      st[rr][1] = gCC*st[rr][1] + bf2f(u4.y);
      st[rr][2] = gCC*st[rr][2] + bf2f(u4.z);
      st[rr][3] = gCC*st[rr][3] + bf2f(u4.w);
    }
  }
}

// ---------------- K4: binter = gamma^{tloc} * rk_g @ Wb_g^T, m97-style staged ----------------
__global__ __launch_bounds__(256) void k_binter(const u16* __restrict__ out_bf,
                                                const u16* __restrict__ Wb,
                                                u16* __restrict__ binter,
                                                const float* __restrict__ decay) {
  __shared__ u16 lds[128*136];
  u16* As = lds;
  u16* Bs = lds + 128*64;
  const int tid = threadIdx.x;
  const int lane = tid & 63, w = tid >> 6;
  const int g = lane >> 4, lr = lane & 15;
  const int rl = lane >> 3, cb = (lane & 7) * 8;
  const int m0 = blockIdx.y * 128, n0 = blockIdx.x * 128;
  const int z = blockIdx.z;
  const int b = z / 15, gg = z % 15 + 1;
  const int wm = (w >> 1) * 64, wn = (w & 1) * 64;
  const float gamma = 1.f / (1.f + __builtin_expf(-decay[0]));
  const float l2g = __builtin_log2f(gamma);
  const size_t arow = (size_t)b*Tn + (size_t)gg*GC + m0;
  const size_t brow = (size_t)(b*NG + gg) * Dn * Dn;
  f4_t acc[4][4];
#pragma unroll
  for (int i = 0; i < 4; ++i)
#pragma unroll
    for (int j = 0; j < 4; ++j) acc[i][j] = (f4_t){0.f, 0.f, 0.f, 0.f};

  for (int kb = 0; kb < 8; ++kb) {
    const int k0 = kb * 64;
    __syncthreads();
#pragma unroll
    for (int i = 0; i < 4; ++i) {
      int r0 = (w*4 + i) * 8;
      gload_lds16(&out_bf[(arow + r0 + rl)*Dn + k0 + cb], &As[r0*64]);
      gload_lds16(&Wb[brow + (size_t)(n0 + r0 + rl)*Dn + k0 + cb], &Bs[r0*64]);
    }
    __syncthreads();
#pragma unroll
    for (int kk = 0; kk < 2; ++kk) {
      const int co = kk*32 + g*8;
      bf8_t a[4], bb[4];
#pragma unroll
      for (int mf = 0; mf < 4; ++mf) a[mf] = *(const bf8_t*)&As[(wm + mf*16 + lr)*64 + co];
#pragma unroll
      for (int nf = 0; nf < 4; ++nf) bb[nf] = *(const bf8_t*)&Bs[(wn + nf*16 + lr)*64 + co];
#pragma unroll
      for (int mf = 0; mf < 4; ++mf)
#pragma unroll
        for (int nf = 0; nf < 4; ++nf)
          acc[mf][nf] = MFMA16(a[mf], bb[nf], acc[mf][nf]);
    }
  }
  __syncthreads();
  u16* Cs = lds;  // [128 t][136 d]
#pragma unroll
  for (int mf = 0; mf < 4; ++mf) {
#pragma unroll
    for (int r = 0; r < 4; ++r) {
      const float gp = __builtin_exp2f(l2g * (float)(m0 + wm + mf*16 + g*4 + r));
#pragma unroll
      for (int nf = 0; nf < 4; ++nf)
        Cs[(wm + mf*16 + g*4 + r)*136 + wn + nf*16 + lr] = f2bf(acc[mf][nf][r] * gp);
    }
  }
  __syncthreads();
#pragma unroll
  for (int i = 0; i < 8; ++i) {
    int slot = i * 256 + tid;
    int r = slot >> 4, c8 = (slot & 15) << 3;
    *(us8_t*)&binter[(arow + r)*Dn + n0 + c8] = *(const us8_t*)&Cs[r*136 + c8];
  }
}

// ---------------- K5: intra v9 — 128-row q-tiles, async dbuf wk stage, exp2-free mask ----------------
// grid (16 gg, 4 qt2, 4 b) x 512 thr. LDS 151,552 B (1 WG/CU, 2 waves/SIMD).
__global__ __launch_bounds__(512, 2) void k_intra(const u16* __restrict__ out_bf,
                                                  const u16* __restrict__ vT,
                                                  const u16* __restrict__ binter,
                                                  u16* __restrict__ reads_bf,
                                                  const float* __restrict__ decay) {
  __shared__ u16 WK2[2*64*520];   // wk double-buffer [p][s 64][e 512 (+8 pad)]
  __shared__ u16 PS[128*72];      // P [t 128][s 64 (+8 pad)]
  const int tid = threadIdx.x;
  const int lane = tid & 63, w = tid >> 6;   // 8 waves
  const int g = lane >> 4, lr = lane & 15;
  const int gg = blockIdx.x, qt2 = blockIdx.y, b = blockIdx.z;
  const int jmax = 2*qt2 + 2;
  const float gamma = 1.f / (1.f + __builtin_expf(-decay[0]));
  const float l2g = __builtin_log2f(gamma);
  const size_t bT = (size_t)b * Tn;
  const size_t tbase = bT + (size_t)gg*GC + qt2*128;

  // QKT A-operand: wave w owns t-strip w*16; rk row in regs, loaded once
  bf8_t rk[16];
#pragma unroll
  for (int kk = 0; kk < 16; ++kk)
    rk[kk] = *(const bf8_t*)&out_bf[(tbase + w*16 + lr)*Dn + kk*32 + g*8];

  // PV A-operand base: d row = w*64 + mf*16 + lr (XCD-L2-local via gg swizzle)
  const u16* vbase = vT + ((size_t)b*Dn + w*64 + lr)*Tn + (size_t)gg*GC + g*8;

  // mask factors: gamma^(dd-1) = cj * gt[r] * gs[nf] (exp2-free inner loop)
  float gt[4], gs[4];
#pragma unroll
  for (int r = 0; r < 4; ++r)
    gt[r] = __builtin_exp2f(l2g * (float)(w*16 + g*4 + r));
#pragma unroll
  for (int nf = 0; nf < 4; ++nf)
    gs[nf] = __builtin_exp2f(-l2g * (float)(nf*16 + lr));

  f4_t acc[4][8];   // [mf: d 64][nf: t 128]
#pragma unroll
  for (int i = 0; i < 4; ++i)
#pragma unroll
    for (int j = 0; j < 8; ++j) acc[i][j] = (f4_t){0.f, 0.f, 0.f, 0.f};

#define STAGE_J(JJ, P)                                                        \
  {                                                                           \
    const int sgs = gg*GC + (JJ)*64;                                          \
    u16* sbase = &WK2[(P)*64*520];                                            \
    _Pragma("unroll")                                                         \
    for (int i = 0; i < 8; ++i) {                                             \
      int row = i*8 + w;                                                      \
      int wr = sgs + row - 1;                                                 \
      if (wr < 0) wr = 0;  /* only (gg==0,j==0,row==0); zero-fixed below */   \
      gload_lds16(&out_bf[(bT + (size_t)wr)*Dn + lane*8], &sbase[row*520]);   \
    }                                                                         \
  }

  STAGE_J(0, 0);
  __syncthreads();                 // drain stage(0)
  if (gg == 0 && tid < 64) {       // global t=0: wk row is zero
    us8_t z = {0,0,0,0,0,0,0,0};
    *(us8_t*)&WK2[tid*8] = z;
  }
  __syncthreads();

  for (int j = 0; j < jmax; ++j) {
    const int p = j & 1;
    if (j + 1 < jmax) STAGE_J(j + 1, p ^ 1);   // async prefetch, drains at (B)
    const u16* buf = &WK2[p*64*520];
    f4_t sacc[4];
#pragma unroll
    for (int i = 0; i < 4; ++i) sacc[i] = (f4_t){0.f, 0.f, 0.f, 0.f};
#pragma unroll
    for (int kk = 0; kk < 16; ++kk) {
      const int co = kk*32 + g*8;
#pragma unroll
      for (int nf = 0; nf < 4; ++nf) {
        bf8_t bb = *(const bf8_t*)&buf[(nf*16 + lr)*520 + co];
        sacc[nf] = MFMA16(rk[kk], bb, sacc[nf]);
      }
    }
    // mask+decay -> PS[t][s]; thread holds tt = w*16+g*4+r, ss = nf*16+lr
    const int off = qt2*128 - j*64;
    const float cj = __builtin_exp2f(l2g * (float)(off - 1));
#pragma unroll
    for (int nf = 0; nf < 4; ++nf) {
      const float cn = cj * gs[nf];
#pragma unroll
      for (int r = 0; r < 4; ++r) {
        const int tt = w*16 + g*4 + r;
        const int ss = nf*16 + lr;
        const int dd = off + tt - ss;
        float mval = (dd > 0) ? (cn * gt[r]) : 0.f;
        PS[tt*72 + ss] = f2bf(sacc[nf][r] * mval);
      }
    }
    __syncthreads();   // (B): PS visible; stage(j+1) drained
    // PV: acc[d][t] += vT x P over this s-block
#pragma unroll
    for (int kk = 0; kk < 2; ++kk) {
      const int co = kk*32 + g*8;
      bf8_t a[4], bb[8];
#pragma unroll
      for (int mf = 0; mf < 4; ++mf)
        a[mf] = *(const bf8_t*)(vbase + (size_t)(mf*16)*Tn + j*64 + kk*32);
#pragma unroll
      for (int nf = 0; nf < 8; ++nf) bb[nf] = *(const bf8_t*)&PS[(nf*16 + lr)*72 + co];
#pragma unroll
      for (int mf = 0; mf < 4; ++mf)
#pragma unroll
        for (int nf = 0; nf < 8; ++nf)
          acc[mf][nf] = MFMA16(a[mf], bb[nf], acc[mf][nf]);
    }
    __syncthreads();   // (A'): PV done with PS; buf p free for stage(j+2)
  }
#undef STAGE_J

  // epilogue: two d-half passes via EP = WK2 [128 t][264]; binter prefetched to regs
  u16* EP = WK2;
#pragma unroll
  for (int pp = 0; pp < 2; ++pp) {
    us8_t bv[8];
    if (gg > 0) {
#pragma unroll
      for (int i = 0; i < 8; ++i) {
        int slot = i*512 + tid;
        int t = slot >> 5, d8 = (slot & 31) << 3;
        bv[i] = *(const us8_t*)&binter[(tbase + t)*Dn + pp*256 + d8];
      }
    }
    __syncthreads();
    if ((w >> 2) == pp) {
      const int wq = w & 3;
#pragma unroll
      for (int mf = 0; mf < 4; ++mf)
#pragma unroll
        for (int nf = 0; nf < 8; ++nf)
#pragma unroll
          for (int r = 0; r < 4; ++r)
            EP[(nf*16 + lr)*264 + wq*64 + mf*16 + g*4 + r] = f2bf(acc[mf][nf][r]);
    }
    __syncthreads();
#pragma unroll
    for (int i = 0; i < 8; ++i) {
      int slot = i*512 + tid;
      int t = slot >> 5, d8 = (slot & 31) << 3;
      us8_t ev = *(const us8_t*)&EP[t*264 + d8];
      us8_t o;
      if (gg > 0) {
#pragma unroll
        for (int k = 0; k < 8; ++k) o[k] = f2bf(bf2f(ev[k]) + bf2f(bv[i][k]));
      } else {
        o = ev;
      }
      *(us8_t*)&reads_bf[(tbase + t)*Dn + pp*256 + d8] = o;
    }
  }
}

// ---------------- K6: out = resid + alpha * (reads @ w_read^T), m97-style staged ----------------
__global__ __launch_bounds__(256) void k_final(const u16* __restrict__ A,
                                               const u16* __restrict__ Bm,
                                               const float* __restrict__ resid,
                                               float* __restrict__ Cout) {
  __shared__ u16 lds[128*64*2];
  u16* As = lds;
  u16* Bs = lds + 128*64;
  const int tid = threadIdx.x;
  const int lane = tid & 63, w = tid >> 6;
  const int g = lane >> 4, lr = lane & 15;
  const int rl = lane >> 3, cb = (lane & 7) * 8;
  const int m0 = blockIdx.y * 128, n0 = blockIdx.x * 128;
  const int wm = (w >> 1) * 64, wn = (w & 1) * 64;
  f4_t acc[4][4];
#pragma unroll
  for (int i = 0; i < 4; ++i)
#pragma unroll
    for (int j = 0; j < 4; ++j) acc[i][j] = (f4_t){0.f, 0.f, 0.f, 0.f};

  for (int kb = 0; kb < 8; ++kb) {
    const int k0 = kb * 64;
    __syncthreads();
#pragma unroll
    for (int i = 0; i < 4; ++i) {
      int r0 = (w*4 + i) * 8;
      gload_lds16(&A[(size_t)(m0 + r0 + rl)*Dn + k0 + cb], &As[r0*64]);
      gload_lds16(&Bm[(size_t)(n0 + r0 + rl)*Dn + k0 + cb], &Bs[r0*64]);
    }
    __syncthreads();
#pragma unroll
    for (int kk = 0; kk < 2; ++kk) {
      const int co = kk*32 + g*8;
      bf8_t a[4], b[4];
#pragma unroll
      for (int mf = 0; mf < 4; ++mf) a[mf] = *(const bf8_t*)&As[(wm + mf*16 + lr)*64 + co];
#pragma unroll
      for (int nf = 0; nf < 4; ++nf) b[nf] = *(const bf8_t*)&Bs[(wn + nf*16 + lr)*64 + co];
#pragma unroll
      for (int mf = 0; mf < 4; ++mf)
#pragma unroll
        for (int nf = 0; nf < 4; ++nf)
          acc[mf][nf] = MFMA16(a[mf], b[nf], acc[mf][nf]);
    }
  }
#pragma unroll
  for (int mf = 0; mf < 4; ++mf)
#pragma unroll
    for (int nf = 0; nf < 4; ++nf)
#pragma unroll
      for (int r = 0; r < 4; ++r) {
        int row = m0 + wm + mf*16 + g*4 + r;
        int col = n0 + wn + nf*16 + lr;
        int idx = row * Dn + col;
        Cout[idx] = resid[idx] + ALPHAc * acc[mf][nf][r];
      }
}

extern "C" void kernel_launch(void* const* d_in, const int* in_sizes, int n_in,
                              void* d_out, int out_size, void* d_ws, size_t ws_size,
                              hipStream_t stream) {
  const float* out_f   = (const float*)d_in[0];
  const float* w_write = (const float*)d_in[1];
  const float* w_read  = (const float*)d_in[2];
  const float* decay   = (const float*)d_in[3];
  float* outp = (float*)d_out;

  char* ws = (char*)d_ws;
  // NON-ALIASED layout (replay-overlap safe). Total 235,929,600 B.
  u16*   out_bf = (u16*)(ws);
  u16*   wkTg   = (u16*)(ws + (size_t)33554432);
  u16*   vT     = (u16*)(ws + (size_t)67108864);
  u16*   wwt_bf = (u16*)(ws + (size_t)100663296);
  u16*   wrd_bf = (u16*)(ws + (size_t)101187584);
  u16*   U      = (u16*)(ws + (size_t)101711872);
  u16*   binter = (u16*)(ws + (size_t)135266304);
  u16*   reads  = (u16*)(ws + (size_t)168820736);
  u16*   Wb     = (u16*)(ws + (size_t)202375168);

  k_convert3<<<16896, 256, 0, stream>>>(out_f, w_write, w_read, out_bf, wwt_bf, wrd_bf);
  k_wkT<<<dim3(64, 4, 4), 256, 0, stream>>>(out_bf, wkTg, decay);
  k_gemm_v<<<dim3(4, 256), 256, 0, stream>>>(out_bf, wwt_bf, vT);
  k_gemm_u<<<dim3(4, 4, 64), 256, 0, stream>>>(vT, wkTg, U);
  k_bscan<<<dim3(8, 8, 4), 256, 0, stream>>>(U, Wb, decay);
  k_binter<<<dim3(4, 4, 60), 256, 0, stream>>>(out_bf, Wb, binter, decay);
  k_intra<<<dim3(16, 4, 4), 512, 0, stream>>>(out_bf, vT, binter, reads, decay);
  k_final<<<dim3(4, 256), 256, 0, stream>>>(reads, wrd_bf, out_f, outp);
}